// Round 3
// baseline (100.927 us; speedup 1.0000x reference)
//
#include <hip/hip_runtime.h>
#include <hip/hip_bf16.h>

#define B_SZ    128
#define IN_F    512
#define OUT_F   128
#define KD      32
#define NC      4096    // OUT_F*KD
#define OUT_COLS 640    // IN_F + OUT_F

// m[b][c] = sum_in x[b][in] * T[in][c], stored as m_ws[(o*128 + b)*32 + k], c = o*32+k
__global__ __launch_bounds__(256) void gemm_kernel(
    const float* __restrict__ x,            // fp32 [128,512]
    const float* __restrict__ T,            // fp32 [512,4096]
    float* __restrict__ m_ws)               // fp32 [128 o][128 b][32 k]
{
    __shared__ float xs[8 * IN_F];          // 16 KB: 8 rows of x
    const int tid = threadIdx.x;
    const int b0  = blockIdx.y * 8;
    const int c   = blockIdx.x * 256 + tid;

    // stage 8 rows of x (coalesced float4)
    const float4* xrow = (const float4*)(x + b0 * IN_F);
    for (int idx = tid; idx < 8 * IN_F / 4; idx += 256)
        ((float4*)xs)[idx] = xrow[idx];
    __syncthreads();

    float acc[8];
    #pragma unroll
    for (int i = 0; i < 8; ++i) acc[i] = 0.f;

    for (int in = 0; in < IN_F; in += 8) {
        float tv[8];
        #pragma unroll
        for (int u = 0; u < 8; ++u) tv[u] = T[(in + u) * NC + c];       // coalesced 1KB/wave
        #pragma unroll
        for (int bb = 0; bb < 8; ++bb) {
            const float4 xv0 = *(const float4*)&xs[bb * IN_F + in];     // LDS broadcast
            const float4 xv1 = *(const float4*)&xs[bb * IN_F + in + 4];
            acc[bb] += xv0.x*tv[0] + xv0.y*tv[1] + xv0.z*tv[2] + xv0.w*tv[3]
                     + xv1.x*tv[4] + xv1.y*tv[5] + xv1.z*tv[6] + xv1.w*tv[7];
        }
    }
    const int o = c >> 5, k = c & 31;
    #pragma unroll
    for (int bb = 0; bb < 8; ++bb)
        m_ws[(o * B_SZ + b0 + bb) * KD + k] = acc[bb];   // lanes 0..31 contiguous per o-group
}

// o_b[j][o] = sum_i exp(-sum_k |m[i,o,k]-m[j,o,k]|) - 1 ; also copies x into out[:, :512]
__global__ __launch_bounds__(512) void pairwise_kernel(
    const float* __restrict__ x,
    const float* __restrict__ m_ws,
    float* __restrict__ out)                // fp32 [128, 640]
{
    __shared__ float mo[B_SZ * KD];         // 16 KB: m[:, o, :]
    __shared__ float psum[64 * 8];

    const int tid   = threadIdx.x;
    const int o     = blockIdx.x >> 1;
    const int jhalf = blockIdx.x & 1;

    // fused x -> out[:, 0:512] copy (fp32 -> fp32, bit-exact)
    // 256 blocks x 64 threads x 1 float4 = 65536 floats = all of x
    if (tid < 64) {
        int idx = blockIdx.x * 64 + tid;    // float4 index, 16384 total
        int b = idx >> 7, c4 = idx & 127;
        float4 v = ((const float4*)x)[idx];
        *(float4*)(out + b * OUT_COLS + c4 * 4) = v;     // 16B-aligned: (2560*b + 16*c4) bytes
    }

    // stage m[:, o, :] (4096 floats, coalesced float4)
    const float4* src = (const float4*)(m_ws + o * (B_SZ * KD));
    for (int idx = tid; idx < (B_SZ * KD) / 4; idx += 512)
        ((float4*)mo)[idx] = src[idx];
    __syncthreads();

    const int jj  = tid & 63;               // wave-local j
    const int isl = tid >> 6;               // i-slice, uniform per wave
    const int j   = jhalf * 64 + jj;

    // m_j fragment in registers — load from GLOBAL (L2) to avoid 64-way LDS bank conflict
    float mj[KD];
    #pragma unroll
    for (int k4 = 0; k4 < 8; ++k4) {
        float4 v = ((const float4*)(m_ws + o * (B_SZ * KD) + j * KD))[k4];
        mj[k4*4+0] = v.x; mj[k4*4+1] = v.y; mj[k4*4+2] = v.z; mj[k4*4+3] = v.w;
    }

    float s = 0.f;
    const int i0 = isl * 16;
    for (int i = i0; i < i0 + 16; ++i) {
        float norm = 0.f;
        #pragma unroll
        for (int k4 = 0; k4 < 8; ++k4) {
            float4 v = ((const float4*)mo)[i * 8 + k4];   // LDS broadcast, conflict-free
            norm += fabsf(mj[k4*4+0] - v.x) + fabsf(mj[k4*4+1] - v.y)
                  + fabsf(mj[k4*4+2] - v.z) + fabsf(mj[k4*4+3] - v.w);
        }
        s += __expf(-norm);                 // i==j contributes exp(0)=1; the -1 removes it
    }
    psum[jj * 8 + isl] = s;
    __syncthreads();
    if (tid < 64) {
        float tot = 0.f;
        #pragma unroll
        for (int u = 0; u < 8; ++u) tot += psum[tid * 8 + u];
        out[(jhalf * 64 + tid) * OUT_COLS + IN_F + o] = tot - 1.0f;
    }
}

extern "C" void kernel_launch(void* const* d_in, const int* in_sizes, int n_in,
                              void* d_out, int out_size, void* d_ws, size_t ws_size,
                              hipStream_t stream) {
    const float* x = (const float*)d_in[0];
    const float* T = (const float*)d_in[1];
    float* out = (float*)d_out;
    float* m_ws = (float*)d_ws;             // needs 128*128*32*4 = 2 MB

    gemm_kernel<<<dim3(16, 16), 256, 0, stream>>>(x, T, m_ws);
    pairwise_kernel<<<256, 512, 0, stream>>>(x, m_ws, out);
}

// Round 4
// 93.776 us; speedup vs baseline: 1.0763x; 1.0763x over previous
//
#include <hip/hip_runtime.h>
#include <hip/hip_bf16.h>

#define B_SZ    128
#define IN_F    512
#define OUT_F   128
#define KD      32
#define NC      4096    // OUT_F*KD
#define OUT_COLS 640    // IN_F + OUT_F
#define KC      8       // K-split chunks
#define KCHUNK  64      // IN_F / KC
#define PART_STRIDE (B_SZ * NC)   // 524288 floats per partial buffer
#define MO_PITCH 36     // padded LDS pitch for mo (32 + 4)

// Partial GEMM: m_part[kc][(o*128+b)*32+k] = sum_{in in chunk} x[b][in]*T[in][c], c=o*32+k
// No LDS: x reads are wave-uniform -> scalar loads; loop is pure v_fmac.
__global__ __launch_bounds__(256, 4) void gemm_kernel(
    const float* __restrict__ x,            // fp32 [128,512]
    const float* __restrict__ T,            // fp32 [512,4096]
    float* __restrict__ m_part)             // fp32 [8][128*4096]
{
    const int tid = threadIdx.x;
    const int c   = blockIdx.x * 256 + tid;     // lane-consecutive columns
    const int b0  = blockIdx.y * 16;            // 16 batch rows per block
    const int k0  = blockIdx.z * KCHUNK;        // K-chunk

    float acc[16];
    #pragma unroll
    for (int i = 0; i < 16; ++i) acc[i] = 0.f;

    for (int in = k0; in < k0 + KCHUNK; in += 8) {
        float tv[8];
        #pragma unroll
        for (int u = 0; u < 8; ++u) tv[u] = T[(in + u) * NC + c];   // coalesced 256B/wave each
        #pragma unroll
        for (int bb = 0; bb < 16; ++bb) {
            // uniform address -> s_load_dwordx4; FMA with SGPR srcs
            const float4 xv0 = *(const float4*)&x[(b0 + bb) * IN_F + in];
            const float4 xv1 = *(const float4*)&x[(b0 + bb) * IN_F + in + 4];
            acc[bb] += xv0.x*tv[0] + xv0.y*tv[1] + xv0.z*tv[2] + xv0.w*tv[3]
                     + xv1.x*tv[4] + xv1.y*tv[5] + xv1.z*tv[6] + xv1.w*tv[7];
        }
    }
    const int o = c >> 5, k = c & 31;
    float* dst = m_part + blockIdx.z * PART_STRIDE;
    #pragma unroll
    for (int bb = 0; bb < 16; ++bb)
        dst[(o * B_SZ + b0 + bb) * KD + k] = acc[bb];   // 32 lanes contiguous per o-group
}

// o_b[j][o] = sum_i exp(-sum_k |m[i,o,k]-m[j,o,k]|) - 1 ; also copies x into out[:, :512]
// Sums the 8 K-partials during staging; mo padded to pitch 36 so mj reads from LDS
// are only 8-way conflicted (one-time).
__global__ __launch_bounds__(1024, 4) void pairwise_kernel(
    const float* __restrict__ x,
    const float* __restrict__ m_part,
    float* __restrict__ out)                // fp32 [128, 640]
{
    __shared__ float mo[B_SZ * MO_PITCH];   // 18 KB, padded
    __shared__ float psum[64 * 16];

    const int tid   = threadIdx.x;
    const int o     = blockIdx.x >> 1;
    const int jhalf = blockIdx.x & 1;

    // fused x -> out[:, 0:512] copy (bit-exact)
    if (tid < 64) {
        int idx = blockIdx.x * 64 + tid;    // float4 index, 16384 total = all of x
        int b = idx >> 7, c4 = idx & 127;
        float4 v = ((const float4*)x)[idx];
        *(float4*)(out + b * OUT_COLS + c4 * 4) = v;
    }

    // stage + reduce partials: thread t owns float4 (i = t>>3, k4 = t&7)
    {
        const int i  = tid >> 3;
        const int k4 = tid & 7;
        const float* src = m_part + o * (B_SZ * KD) + tid * 4;
        float4 s = *(const float4*)src;
        #pragma unroll
        for (int p = 1; p < KC; ++p) {
            float4 v = *(const float4*)(src + p * PART_STRIDE);
            s.x += v.x; s.y += v.y; s.z += v.z; s.w += v.w;
        }
        *(float4*)&mo[i * MO_PITCH + k4 * 4] = s;
    }
    __syncthreads();

    const int jj  = tid & 63;               // wave-local j
    const int isl = tid >> 6;               // i-slice (0..15), uniform per wave
    const int j   = jhalf * 64 + jj;

    // m_j fragment from padded LDS (8-way b128 conflict, one-time)
    float mj[KD];
    #pragma unroll
    for (int k4 = 0; k4 < 8; ++k4) {
        float4 v = *(const float4*)&mo[j * MO_PITCH + k4 * 4];
        mj[k4*4+0] = v.x; mj[k4*4+1] = v.y; mj[k4*4+2] = v.z; mj[k4*4+3] = v.w;
    }

    float s = 0.f;
    const int i0 = isl * 8;
    for (int i = i0; i < i0 + 8; ++i) {
        float norm = 0.f;
        #pragma unroll
        for (int k4 = 0; k4 < 8; ++k4) {
            float4 v = *(const float4*)&mo[i * MO_PITCH + k4 * 4];  // broadcast, conflict-free
            norm += fabsf(mj[k4*4+0] - v.x) + fabsf(mj[k4*4+1] - v.y)
                  + fabsf(mj[k4*4+2] - v.z) + fabsf(mj[k4*4+3] - v.w);
        }
        s += __expf(-norm);                 // i==j contributes exp(0)=1; the -1 removes it
    }
    psum[jj * 16 + isl] = s;
    __syncthreads();
    if (tid < 64) {
        float tot = 0.f;
        #pragma unroll
        for (int u = 0; u < 16; ++u) tot += psum[tid * 16 + u];
        out[(jhalf * 64 + tid) * OUT_COLS + IN_F + o] = tot - 1.0f;
    }
}

extern "C" void kernel_launch(void* const* d_in, const int* in_sizes, int n_in,
                              void* d_out, int out_size, void* d_ws, size_t ws_size,
                              hipStream_t stream) {
    const float* x = (const float*)d_in[0];
    const float* T = (const float*)d_in[1];
    float* out = (float*)d_out;
    float* m_part = (float*)d_ws;           // 8 * 2 MB = 16 MB of workspace

    gemm_kernel<<<dim3(16, 8, 8), 256, 0, stream>>>(x, T, m_part);
    pairwise_kernel<<<256, 1024, 0, stream>>>(x, m_part, out);
}